// Round 4
// baseline (223.786 us; speedup 1.0000x reference)
//
#include <hip/hip_runtime.h>

// Problem constants (from reference): B=4, S=2048, D=1024, G=4 -> NG=256, NC=16
constexpr int B_ = 4;
constexpr int S_ = 2048;
constexpr int D_ = 1024;
constexpr int G_ = 4;
constexpr int NG_ = D_ / G_;            // 256
constexpr int NC_ = 1 << G_;            // 16
constexpr int NGROUPS = B_ * S_ * NG_;  // 2,097,152

// Native 4-float vector: __builtin_nontemporal_load/store rejects the
// HIP_vector_type struct float4, but accepts ext_vector_type.
typedef float vfloat4 __attribute__((ext_vector_type(4)));

// One thread per group of G=4 elements.
//
// Algebra: logits = -(z^2 - 2*cross + |c|^2). z^2 and |c|^2 are uniform across
// the 16 codewords of a group -> cancel in softmax. So
//   weights = softmax((2*cross + gumbel)/tau),  quantized = weights @ codebook.
//
// Memory: gumbel 128 MiB + x 32 MiB read, out 32 MiB write — all mandatory.
// R2 showed LDS-staging the gumbel stream is neutral (L1 absorbs the 64B/lane
// stride within a wave), so keep the simple direct-load form. Nontemporal
// hints keep the 192 MiB streaming traffic from thrashing L2/L3.
__global__ __launch_bounds__(256) void gumbel_quant_kernel(
    const float* __restrict__ x,        // [B,S,D]
    const float* __restrict__ gumbel,   // [B,S,NG,NC]
    const float* __restrict__ codebook, // [NC,G]
    const float* __restrict__ log_temp, // scalar
    float* __restrict__ out)            // [B,S,D]
{
    const int idx = blockIdx.x * blockDim.x + threadIdx.x;
    if (idx >= NGROUPS) return;

    // tau = clip(exp(log_temp), 0.05, 5.0); uniform across all threads
    float tau = __expf(log_temp[0]);
    tau = fminf(fmaxf(tau, 0.05f), 5.0f);
    const float inv_tau = 1.0f / tau;

    // Codebook: 64 uniform floats -> scalar loads, broadcast to all lanes.
    float cb[NC_][G_];
#pragma unroll
    for (int c = 0; c < NC_; ++c)
#pragma unroll
        for (int j = 0; j < G_; ++j)
            cb[c][j] = codebook[c * G_ + j];

    // Group input: one coalesced 16B load per lane (read-once -> nontemporal).
    const vfloat4 xg =
        __builtin_nontemporal_load(reinterpret_cast<const vfloat4*>(x) + idx);
    const float xs[G_] = {xg.x, xg.y, xg.z, xg.w};

    // Gumbel noise: 16 floats = 4 x 16B loads per lane (read-once -> nontemporal).
    const vfloat4* gp = reinterpret_cast<const vfloat4*>(gumbel) + (size_t)idx * 4;
    const vfloat4 gq0 = __builtin_nontemporal_load(gp + 0);
    const vfloat4 gq1 = __builtin_nontemporal_load(gp + 1);
    const vfloat4 gq2 = __builtin_nontemporal_load(gp + 2);
    const vfloat4 gq3 = __builtin_nontemporal_load(gp + 3);
    const float gv[NC_] = {gq0.x, gq0.y, gq0.z, gq0.w,
                           gq1.x, gq1.y, gq1.z, gq1.w,
                           gq2.x, gq2.y, gq2.z, gq2.w,
                           gq3.x, gq3.y, gq3.z, gq3.w};

    // vals[c] = (2*cross[c] + gumbel[c]) / tau, track max for stable softmax
    float vals[NC_];
    float m = -INFINITY;
#pragma unroll
    for (int c = 0; c < NC_; ++c) {
        float cross = cb[c][0] * xs[0];
        cross = fmaf(cb[c][1], xs[1], cross);
        cross = fmaf(cb[c][2], xs[2], cross);
        cross = fmaf(cb[c][3], xs[3], cross);
        const float v = fmaf(2.0f, cross, gv[c]) * inv_tau;
        vals[c] = v;
        m = fmaxf(m, v);
    }

    // exp + sum
    float w[NC_];
    float sum = 0.0f;
#pragma unroll
    for (int c = 0; c < NC_; ++c) {
        const float e = __expf(vals[c] - m);
        w[c] = e;
        sum += e;
    }
    const float inv_sum = 1.0f / sum;

    // quantized[j] = (sum_c w[c]*cb[c][j]) / sum
    float q[G_] = {0.0f, 0.0f, 0.0f, 0.0f};
#pragma unroll
    for (int c = 0; c < NC_; ++c) {
#pragma unroll
        for (int j = 0; j < G_; ++j)
            q[j] = fmaf(w[c], cb[c][j], q[j]);
    }

    vfloat4 o;
    o.x = q[0] * inv_sum;
    o.y = q[1] * inv_sum;
    o.z = q[2] * inv_sum;
    o.w = q[3] * inv_sum;
    __builtin_nontemporal_store(o, reinterpret_cast<vfloat4*>(out) + idx);
}

extern "C" void kernel_launch(void* const* d_in, const int* in_sizes, int n_in,
                              void* d_out, int out_size, void* d_ws, size_t ws_size,
                              hipStream_t stream) {
    const float* x        = (const float*)d_in[0];
    const float* gumbel   = (const float*)d_in[1];
    const float* codebook = (const float*)d_in[2];
    const float* log_temp = (const float*)d_in[3];
    float* out = (float*)d_out;

    constexpr int block = 256;
    constexpr int grid = (NGROUPS + block - 1) / block;  // 8192 blocks
    gumbel_quant_kernel<<<grid, block, 0, stream>>>(x, gumbel, codebook, log_temp, out);
}